// Round 1
// baseline (4587.137 us; speedup 1.0000x reference)
//
#include <hip/hip_runtime.h>

typedef float f32x4_t __attribute__((ext_vector_type(4)));
typedef short bf16x8_t __attribute__((ext_vector_type(8)));

#define MFMA16(A,B,C) __builtin_amdgcn_mfma_f32_16x16x32_bf16((A),(B),(C),0,0,0)

static constexpr int CC = 256;      // channels
static constexpr int NP = 3600;     // valid tokens
static constexpr int PP = 3648;     // padded tokens (57*64)
static constexpr int CPOS = 3906;   // canvas positions (62*63, incl. slack)
static constexpr int NQT = 57;      // 64-row tiles over PP

static constexpr size_t SZ_F  = (size_t)PP*CC*4;     // 3,735,552
static constexpr size_t SZ_H  = (size_t)PP*CC*2;     // 1,867,776
static constexpr size_t SZ_CV = (size_t)CPOS*512*2;  // 3,999,744

static constexpr size_t O_SF   = 0;                  // 3x f32 state (token-major)
static constexpr size_t O_STH  = O_SF   + 3*SZ_F;    // state bf16 hi token-major
static constexpr size_t O_STL  = O_STH  + 3*SZ_H;
static constexpr size_t O_SCH  = O_STL  + 3*SZ_H;    // state bf16 hi channel-major
static constexpr size_t O_SCL  = O_SCH  + 3*SZ_H;
static constexpr size_t O_CORH = O_SCL  + 3*SZ_H;    // corr hi/lo token-major
static constexpr size_t O_CORL = O_CORH + 3*SZ_H;
static constexpr size_t O_CVH  = O_CORL + 3*SZ_H;    // 3 canvases hi
static constexpr size_t O_CVL  = O_CVH  + 3*SZ_CV;   // 3 canvases lo
static constexpr size_t O_AH   = O_CVL  + 3*SZ_CV;   // conv out hi/lo
static constexpr size_t O_AL   = O_AH   + 3*SZ_H;
static constexpr size_t O_U    = O_AL   + 3*SZ_H;    // u gate f32
static constexpr size_t O_PRH  = O_U    + 3*SZ_F;    // prev*r hi/lo
static constexpr size_t O_PRL  = O_PRH  + 3*SZ_H;
static constexpr size_t O_WLH  = O_PRL  + 3*SZ_H;    // W_lin 256x256
static constexpr size_t O_WLL  = O_WLH  + 131072;
static constexpr size_t O_WURH = O_WLL  + 131072;    // [W_update;W_reset] 512x512
static constexpr size_t O_WURL = O_WURH + 524288;
static constexpr size_t O_WOH  = O_WURL + 524288;    // W_out 256x512
static constexpr size_t O_WOL  = O_WOH  + 262144;
static constexpr size_t O_WKH  = O_WOL  + 262144;    // conv weights 9x256x512
static constexpr size_t O_WKL  = O_WKH  + 2359296;

#define WSPTR(T, OFF) ((T*)(ws + (OFF)))

__device__ __forceinline__ unsigned short f2bf(float f){
  unsigned u = __builtin_bit_cast(unsigned, f);
  u += 0x7FFFu + ((u >> 16) & 1u);
  return (unsigned short)(u >> 16);
}
__device__ __forceinline__ float bf2f(unsigned short h){
  unsigned u = ((unsigned)h) << 16;
  return __builtin_bit_cast(float, u);
}
__device__ __forceinline__ void split_bf(float x, unsigned short &h, unsigned short &l){
  h = f2bf(x);
  l = f2bf(x - bf2f(h));
}

// ---- shared GEMM pieces: 64x64 tile, K-step 64, LDS stride 72 -------------
__device__ __forceinline__ void stage64(unsigned short* dst, const unsigned short* __restrict__ src, int ld){
  int t = threadIdx.x, r = t >> 2, c8 = (t & 3) * 8;
  *(bf16x8_t*)&dst[r*72 + c8]      = *(const bf16x8_t*)&src[(size_t)r*ld + c8];
  *(bf16x8_t*)&dst[r*72 + c8 + 32] = *(const bf16x8_t*)&src[(size_t)r*ld + c8 + 32];
}

__device__ __forceinline__ void mfma64(const unsigned short* Ah, const unsigned short* Al,
                                       const unsigned short* Bh, const unsigned short* Bl,
                                       f32x4_t acc[4], int lane, int wid){
  int kb = (lane >> 4) * 8, lr = lane & 15;
  int arow = wid*16 + lr;
  #pragma unroll
  for(int kk = 0; kk < 2; kk++){
    bf16x8_t ah = *(const bf16x8_t*)&Ah[arow*72 + kk*32 + kb];
    bf16x8_t al = *(const bf16x8_t*)&Al[arow*72 + kk*32 + kb];
    #pragma unroll
    for(int ct = 0; ct < 4; ct++){
      int brow = ct*16 + lr;
      bf16x8_t bh = *(const bf16x8_t*)&Bh[brow*72 + kk*32 + kb];
      bf16x8_t bl = *(const bf16x8_t*)&Bl[brow*72 + kk*32 + kb];
      acc[ct] = MFMA16(ah, bh, acc[ct]);
      acc[ct] = MFMA16(ah, bl, acc[ct]);
      acc[ct] = MFMA16(al, bh, acc[ct]);
    }
  }
}

// ---- zero canvases --------------------------------------------------------
__global__ void k_zero(char* ws){
  size_t n = (6*SZ_CV)/16;
  uint4* p = (uint4*)(ws + O_CVH);
  uint4 z = {0,0,0,0};
  for(size_t x = (size_t)blockIdx.x*256 + threadIdx.x; x < n; x += (size_t)gridDim.x*256) p[x] = z;
}

// ---- split weights --------------------------------------------------------
__global__ void k_weights(char* ws, const float* __restrict__ Wlin, const float* __restrict__ Wup,
                          const float* __restrict__ Wrs, const float* __restrict__ Wo,
                          const float* __restrict__ Wcf){
  const size_t N1 = 65536, N2 = N1 + 262144, N3 = N2 + 131072, N4 = N3 + 1179648;
  for(size_t x = (size_t)blockIdx.x*256 + threadIdx.x; x < N4; x += (size_t)gridDim.x*256){
    float v; unsigned short *dh, *dl; size_t off;
    if(x < N1){
      v = Wlin[x]; dh = WSPTR(unsigned short, O_WLH); dl = WSPTR(unsigned short, O_WLL); off = x;
    } else if(x < N2){
      size_t i = x - N1; int e = (int)(i >> 9), c = (int)(i & 511);
      v = (e < 256) ? Wup[(size_t)e*512 + c] : Wrs[(size_t)(e-256)*512 + c];
      dh = WSPTR(unsigned short, O_WURH); dl = WSPTR(unsigned short, O_WURL); off = i;
    } else if(x < N3){
      size_t i = x - N2; v = Wo[i];
      dh = WSPTR(unsigned short, O_WOH); dl = WSPTR(unsigned short, O_WOL); off = i;
    } else {
      size_t i = x - N3; int t = (int)(i % 9); size_t rest = i / 9;
      int ic = (int)(rest & 511), o = (int)(rest >> 9);
      v = Wcf[i]; off = (size_t)t*131072 + (size_t)o*512 + ic;
      dh = WSPTR(unsigned short, O_WKH); dl = WSPTR(unsigned short, O_WKL);
    }
    unsigned short h, l; split_bf(v, h, l);
    dh[off] = h; dl[off] = l;
  }
}

// ---- transpose inputs to token-major + make bf16 copies -------------------
__global__ __launch_bounds__(256) void k_transpose(char* ws, const float* __restrict__ in0,
                                                   const float* __restrict__ in1, const float* __restrict__ in2){
  __shared__ float tile[64*65];
  int z = blockIdx.z;
  const float* in = z == 0 ? in0 : (z == 1 ? in1 : in2);
  int p0 = blockIdx.x*64, c0 = blockIdx.y*64;
  float* sF = WSPTR(float, O_SF) + (size_t)z*PP*CC;
  unsigned short* sTh = WSPTR(unsigned short, O_STH) + (size_t)z*PP*CC;
  unsigned short* sTl = WSPTR(unsigned short, O_STL) + (size_t)z*PP*CC;
  unsigned short* sCh = WSPTR(unsigned short, O_SCH) + (size_t)z*PP*CC;
  unsigned short* sCl = WSPTR(unsigned short, O_SCL) + (size_t)z*PP*CC;
  int t = threadIdx.x, pl = t & 63, cq = t >> 6;
  #pragma unroll
  for(int rr = 0; rr < 16; rr++){
    int cl = rr*4 + cq, p = p0 + pl, c = c0 + cl;
    float v = (p < NP) ? in[(size_t)c*NP + p] : 0.f;
    tile[cl*65 + pl] = v;
    if(p < NP){
      unsigned short h, l; split_bf(v, h, l);
      sCh[(size_t)c*PP + p] = h; sCl[(size_t)c*PP + p] = l;
    }
  }
  __syncthreads();
  #pragma unroll
  for(int rr = 0; rr < 16; rr++){
    int prow = rr*4 + cq, p = p0 + prow, cl = pl;
    if(p < NP){
      float v = tile[cl*65 + prow];
      int c = c0 + cl;
      sF[(size_t)p*CC + c] = v;
      unsigned short h, l; split_bf(v, h, l);
      sTh[(size_t)p*CC + c] = h; sTl[(size_t)p*CC + c] = l;
    }
  }
}

// ---- corr = stateT @ W_lin^T ----------------------------------------------
__global__ __launch_bounds__(256,4) void k_corr(char* ws){
  __shared__ unsigned short Ah[64*72], Al[64*72], Bh[64*72], Bl[64*72];
  int z = blockIdx.z, m0 = blockIdx.x*64, n0 = blockIdx.y*64;
  const unsigned short* aH = WSPTR(const unsigned short, O_STH) + (size_t)z*PP*CC;
  const unsigned short* aL = WSPTR(const unsigned short, O_STL) + (size_t)z*PP*CC;
  const unsigned short* bH = WSPTR(const unsigned short, O_WLH);
  const unsigned short* bL = WSPTR(const unsigned short, O_WLL);
  unsigned short* cH = WSPTR(unsigned short, O_CORH) + (size_t)z*PP*CC;
  unsigned short* cL = WSPTR(unsigned short, O_CORL) + (size_t)z*PP*CC;
  int lane = threadIdx.x & 63, wid = threadIdx.x >> 6;
  f32x4_t acc[4] = {};
  for(int k0 = 0; k0 < 256; k0 += 64){
    __syncthreads();
    stage64(Ah, aH + (size_t)m0*256 + k0, 256);
    stage64(Al, aL + (size_t)m0*256 + k0, 256);
    stage64(Bh, bH + (size_t)n0*256 + k0, 256);
    stage64(Bl, bL + (size_t)n0*256 + k0, 256);
    __syncthreads();
    mfma64(Ah, Al, Bh, Bl, acc, lane, wid);
  }
  #pragma unroll
  for(int r = 0; r < 4; r++){
    int i = m0 + wid*16 + (lane >> 4)*4 + r;
    if(i >= NP) continue;
    #pragma unroll
    for(int ct = 0; ct < 4; ct++){
      int c = n0 + ct*16 + (lane & 15);
      unsigned short h, l; split_bf(acc[ct][r], h, l);
      cH[(size_t)i*CC + c] = h; cL[(size_t)i*CC + c] = l;
    }
  }
}

// ---- flash attention + gate, writes gated att into padded canvas ----------
__global__ __launch_bounds__(256,2) void k_flash(char* ws, const float* __restrict__ wgate){
  __shared__ unsigned short KVh[256*40], KVl[256*40];
  __shared__ unsigned short Pht[4][16*72], Plt[4][16*72];
  int pair = blockIdx.y, bx = blockIdx.x;
  int src = pair >> 1;
  int tgt = ((pair & 1) == 0) ? (src == 0 ? 1 : 0) : (src == 2 ? 1 : 2);
  int cho = (pair & 1) * 256;
  const unsigned short* Qh = WSPTR(const unsigned short, O_CORH) + (size_t)src*PP*CC;
  const unsigned short* Ql = WSPTR(const unsigned short, O_CORL) + (size_t)src*PP*CC;
  const unsigned short* Kh = WSPTR(const unsigned short, O_STH)  + (size_t)tgt*PP*CC;
  const unsigned short* Kl = WSPTR(const unsigned short, O_STL)  + (size_t)tgt*PP*CC;
  const unsigned short* Vh = WSPTR(const unsigned short, O_SCH)  + (size_t)tgt*PP*CC;
  const unsigned short* Vl = WSPTR(const unsigned short, O_SCL)  + (size_t)tgt*PP*CC;
  unsigned short* cvH = WSPTR(unsigned short, O_CVH) + (size_t)src*CPOS*512 + cho;
  unsigned short* cvL = WSPTR(unsigned short, O_CVL) + (size_t)src*CPOS*512 + cho;
  int lane = threadIdx.x & 63, wid = threadIdx.x >> 6;
  int lr = lane & 15, lk = lane >> 4;

  bf16x8_t qh[8], ql[8];
  int qrow = bx*64 + wid*16 + lr;
  #pragma unroll
  for(int kc = 0; kc < 8; kc++){
    qh[kc] = *(const bf16x8_t*)&Qh[(size_t)qrow*256 + kc*32 + lk*8];
    ql[kc] = *(const bf16x8_t*)&Ql[(size_t)qrow*256 + kc*32 + lk*8];
  }
  float m[4] = {-1e38f, -1e38f, -1e38f, -1e38f};
  float lsum[4] = {0.f, 0.f, 0.f, 0.f};
  f32x4_t oacc[16] = {};

  for(int kt = 0; kt < NQT; kt++){
    int j0 = kt*64;
    f32x4_t s[4] = {};
    for(int ks = 0; ks < 4; ks++){
      __syncthreads();
      stage64(KVh, Kh + (size_t)j0*256 + ks*64, 256);
      stage64(KVl, Kl + (size_t)j0*256 + ks*64, 256);
      __syncthreads();
      #pragma unroll
      for(int kk = 0; kk < 2; kk++){
        bf16x8_t a_h = qh[ks*2 + kk], a_l = ql[ks*2 + kk];
        #pragma unroll
        for(int ct = 0; ct < 4; ct++){
          int brow = ct*16 + lr;
          bf16x8_t b_h = *(const bf16x8_t*)&KVh[brow*72 + kk*32 + lk*8];
          bf16x8_t b_l = *(const bf16x8_t*)&KVl[brow*72 + kk*32 + lk*8];
          s[ct] = MFMA16(a_h, b_h, s[ct]);
          s[ct] = MFMA16(a_h, b_l, s[ct]);
          s[ct] = MFMA16(a_l, b_h, s[ct]);
        }
      }
    }
    // mask invalid columns
    #pragma unroll
    for(int ct = 0; ct < 4; ct++){
      int j = j0 + ct*16 + lr;
      if(j >= NP){ s[ct][0] = -1e30f; s[ct][1] = -1e30f; s[ct][2] = -1e30f; s[ct][3] = -1e30f; }
    }
    float mn[4], sc[4];
    #pragma unroll
    for(int r = 0; r < 4; r++){
      float v = fmaxf(fmaxf(s[0][r], s[1][r]), fmaxf(s[2][r], s[3][r]));
      #pragma unroll
      for(int d = 8; d >= 1; d >>= 1) v = fmaxf(v, __shfl_xor(v, d, 16));
      mn[r] = fmaxf(m[r], v);
      sc[r] = __expf(m[r] - mn[r]);
      m[r] = mn[r];
      lsum[r] *= sc[r];
    }
    #pragma unroll
    for(int ct = 0; ct < 16; ct++){
      #pragma unroll
      for(int r = 0; r < 4; r++) oacc[ct][r] *= sc[r];
    }
    float ps[4] = {0.f, 0.f, 0.f, 0.f};
    #pragma unroll
    for(int ct = 0; ct < 4; ct++){
      #pragma unroll
      for(int r = 0; r < 4; r++){
        float p = __expf(s[ct][r] - mn[r]);
        ps[r] += p;
        unsigned short h, l; split_bf(p, h, l);
        Pht[wid][(lk*4 + r)*72 + ct*16 + lr] = h;
        Plt[wid][(lk*4 + r)*72 + ct*16 + lr] = l;
      }
    }
    #pragma unroll
    for(int r = 0; r < 4; r++){
      float v = ps[r];
      #pragma unroll
      for(int d = 8; d >= 1; d >>= 1) v += __shfl_xor(v, d, 16);
      lsum[r] += v;
    }
    // PV
    for(int kk = 0; kk < 2; kk++){
      __syncthreads();
      {
        int t = threadIdx.x;
        #pragma unroll
        for(int it = 0; it < 4; it++){
          int task = t + 256*it;
          int c = task >> 2, j8 = (task & 3)*8;
          *(bf16x8_t*)&KVh[c*40 + j8] = *(const bf16x8_t*)&Vh[(size_t)c*PP + j0 + kk*32 + j8];
          *(bf16x8_t*)&KVl[c*40 + j8] = *(const bf16x8_t*)&Vl[(size_t)c*PP + j0 + kk*32 + j8];
        }
      }
      __syncthreads();
      bf16x8_t pa_h = *(const bf16x8_t*)&Pht[wid][lr*72 + kk*32 + lk*8];
      bf16x8_t pa_l = *(const bf16x8_t*)&Plt[wid][lr*72 + kk*32 + lk*8];
      #pragma unroll
      for(int ct = 0; ct < 16; ct++){
        bf16x8_t v_h = *(const bf16x8_t*)&KVh[(ct*16 + lr)*40 + lk*8];
        bf16x8_t v_l = *(const bf16x8_t*)&KVl[(ct*16 + lr)*40 + lk*8];
        oacc[ct] = MFMA16(pa_h, v_h, oacc[ct]);
        oacc[ct] = MFMA16(pa_h, v_l, oacc[ct]);
        oacc[ct] = MFMA16(pa_l, v_h, oacc[ct]);
      }
    }
  }
  // epilogue: normalize, gate, write canvas interior
  #pragma unroll
  for(int r = 0; r < 4; r++){
    int i = bx*64 + wid*16 + lk*4 + r;
    float inv = 1.f / lsum[r];
    float g = 0.f;
    #pragma unroll
    for(int ct = 0; ct < 16; ct++) g += wgate[ct*16 + lr] * (oacc[ct][r] * inv);
    #pragma unroll
    for(int d = 8; d >= 1; d >>= 1) g += __shfl_xor(g, d, 16);
    g = 1.f / (1.f + __expf(-g));
    if(i < NP){
      int pos = (1 + i/60)*62 + 1 + i%60;
      #pragma unroll
      for(int ct = 0; ct < 16; ct++){
        int c = ct*16 + lr;
        float v = oacc[ct][r] * inv * g;
        unsigned short h, l; split_bf(v, h, l);
        cvH[(size_t)pos*512 + c] = h;
        cvL[(size_t)pos*512 + c] = l;
      }
    }
  }
}

// ---- conv3x3 over canvas (512 -> 256), output token-major hi/lo -----------
__global__ __launch_bounds__(256,4) void k_conv(char* ws, const float* __restrict__ bcf){
  __shared__ unsigned short Ah[64*72], Al[64*72], Bh[64*72], Bl[64*72];
  int z = blockIdx.z, y = blockIdx.x, n0 = blockIdx.y*64;
  const unsigned short* cvH = WSPTR(const unsigned short, O_CVH) + (size_t)z*CPOS*512;
  const unsigned short* cvL = WSPTR(const unsigned short, O_CVL) + (size_t)z*CPOS*512;
  const unsigned short* wH = WSPTR(const unsigned short, O_WKH);
  const unsigned short* wL = WSPTR(const unsigned short, O_WKL);
  unsigned short* oH = WSPTR(unsigned short, O_AH) + (size_t)z*PP*CC;
  unsigned short* oL = WSPTR(unsigned short, O_AL) + (size_t)z*PP*CC;
  int lane = threadIdx.x & 63, wid = threadIdx.x >> 6;
  f32x4_t acc[4] = {};
  for(int t = 0; t < 9; t++){
    int posBase = (y + t/3)*62 + (t%3);
    const unsigned short* aH = cvH + (size_t)posBase*512;
    const unsigned short* aL = cvL + (size_t)posBase*512;
    const unsigned short* bH = wH + (size_t)t*131072 + (size_t)n0*512;
    const unsigned short* bL = wL + (size_t)t*131072 + (size_t)n0*512;
    for(int k0 = 0; k0 < 512; k0 += 64){
      __syncthreads();
      stage64(Ah, aH + k0, 512);
      stage64(Al, aL + k0, 512);
      stage64(Bh, bH + k0, 512);
      stage64(Bl, bL + k0, 512);
      __syncthreads();
      mfma64(Ah, Al, Bh, Bl, acc, lane, wid);
    }
  }
  #pragma unroll
  for(int r = 0; r < 4; r++){
    int x = wid*16 + (lane >> 4)*4 + r;
    if(x >= 60) continue;
    int i = y*60 + x;
    #pragma unroll
    for(int ct = 0; ct < 4; ct++){
      int c = n0 + ct*16 + (lane & 15);
      float v = acc[ct][r] + bcf[c];
      unsigned short h, l; split_bf(v, h, l);
      oH[(size_t)i*CC + c] = h; oL[(size_t)i*CC + c] = l;
    }
  }
}

// ---- GRU gates: u = sigmoid(Wu@[a;prev]), pr = sigmoid(Wr@[a;prev])*prev --
__global__ __launch_bounds__(256,4) void k_gates(char* ws, const float* __restrict__ bu, const float* __restrict__ br){
  __shared__ unsigned short Ah[64*72], Al[64*72], Bh[64*72], Bl[64*72];
  int z = blockIdx.z, m0 = blockIdx.x*64, n0 = blockIdx.y*64;
  const unsigned short* aH0 = WSPTR(const unsigned short, O_AH)  + (size_t)z*PP*CC;
  const unsigned short* aL0 = WSPTR(const unsigned short, O_AL)  + (size_t)z*PP*CC;
  const unsigned short* aH1 = WSPTR(const unsigned short, O_STH) + (size_t)z*PP*CC;
  const unsigned short* aL1 = WSPTR(const unsigned short, O_STL) + (size_t)z*PP*CC;
  const unsigned short* bH  = WSPTR(const unsigned short, O_WURH) + (size_t)n0*512;
  const unsigned short* bL  = WSPTR(const unsigned short, O_WURL) + (size_t)n0*512;
  const float* prevF = WSPTR(const float, O_SF) + (size_t)z*PP*CC;
  float* uOut = WSPTR(float, O_U) + (size_t)z*PP*CC;
  unsigned short* prH = WSPTR(unsigned short, O_PRH) + (size_t)z*PP*CC;
  unsigned short* prL = WSPTR(unsigned short, O_PRL) + (size_t)z*PP*CC;
  int lane = threadIdx.x & 63, wid = threadIdx.x >> 6;
  f32x4_t acc[4] = {};
  for(int ks = 0; ks < 8; ks++){
    const unsigned short* sah = (ks < 4) ? aH0 : aH1;
    const unsigned short* sal = (ks < 4) ? aL0 : aL1;
    int koff = (ks & 3) * 64;
    __syncthreads();
    stage64(Ah, sah + (size_t)m0*256 + koff, 256);
    stage64(Al, sal + (size_t)m0*256 + koff, 256);
    stage64(Bh, bH + ks*64, 512);
    stage64(Bl, bL + ks*64, 512);
    __syncthreads();
    mfma64(Ah, Al, Bh, Bl, acc, lane, wid);
  }
  #pragma unroll
  for(int r = 0; r < 4; r++){
    int i = m0 + wid*16 + (lane >> 4)*4 + r;
    if(i >= NP) continue;
    #pragma unroll
    for(int ct = 0; ct < 4; ct++){
      int c = n0 + ct*16 + (lane & 15);
      float pre = acc[ct][r] + (c < 256 ? bu[c] : br[c - 256]);
      float sg = 1.f / (1.f + __expf(-pre));
      if(c < 256){
        uOut[(size_t)i*CC + c] = sg;
      } else {
        int e = c - 256;
        float pv = prevF[(size_t)i*CC + e];
        unsigned short h, l; split_bf(sg * pv, h, l);
        prH[(size_t)i*CC + e] = h; prL[(size_t)i*CC + e] = l;
      }
    }
  }
}

// ---- GRU out: o = tanh(Wo@[a;pr]); h = prev*(1-u)+o*u; update state -------
__global__ __launch_bounds__(256,4) void k_gruo(char* ws, const float* __restrict__ bo, float* __restrict__ dout, int fin){
  __shared__ unsigned short Ah[64*72], Al[64*72], Bh[64*72], Bl[64*72];
  int z = blockIdx.z, m0 = blockIdx.x*64, n0 = blockIdx.y*64;
  const unsigned short* aH0 = WSPTR(const unsigned short, O_AH)  + (size_t)z*PP*CC;
  const unsigned short* aL0 = WSPTR(const unsigned short, O_AL)  + (size_t)z*PP*CC;
  const unsigned short* aH1 = WSPTR(const unsigned short, O_PRH) + (size_t)z*PP*CC;
  const unsigned short* aL1 = WSPTR(const unsigned short, O_PRL) + (size_t)z*PP*CC;
  const unsigned short* bH  = WSPTR(const unsigned short, O_WOH) + (size_t)n0*512;
  const unsigned short* bL  = WSPTR(const unsigned short, O_WOL) + (size_t)n0*512;
  const float* uBuf = WSPTR(const float, O_U) + (size_t)z*PP*CC;
  float* sF = WSPTR(float, O_SF) + (size_t)z*PP*CC;
  unsigned short* sTh = WSPTR(unsigned short, O_STH) + (size_t)z*PP*CC;
  unsigned short* sTl = WSPTR(unsigned short, O_STL) + (size_t)z*PP*CC;
  unsigned short* sCh = WSPTR(unsigned short, O_SCH) + (size_t)z*PP*CC;
  unsigned short* sCl = WSPTR(unsigned short, O_SCL) + (size_t)z*PP*CC;
  int lane = threadIdx.x & 63, wid = threadIdx.x >> 6;
  f32x4_t acc[4] = {};
  for(int ks = 0; ks < 8; ks++){
    const unsigned short* sah = (ks < 4) ? aH0 : aH1;
    const unsigned short* sal = (ks < 4) ? aL0 : aL1;
    int koff = (ks & 3) * 64;
    __syncthreads();
    stage64(Ah, sah + (size_t)m0*256 + koff, 256);
    stage64(Al, sal + (size_t)m0*256 + koff, 256);
    stage64(Bh, bH + ks*64, 512);
    stage64(Bl, bL + ks*64, 512);
    __syncthreads();
    mfma64(Ah, Al, Bh, Bl, acc, lane, wid);
  }
  #pragma unroll
  for(int r = 0; r < 4; r++){
    int i = m0 + wid*16 + (lane >> 4)*4 + r;
    if(i >= NP) continue;
    #pragma unroll
    for(int ct = 0; ct < 4; ct++){
      int c = n0 + ct*16 + (lane & 15);
      float o = tanhf(acc[ct][r] + bo[c]);
      float uu = uBuf[(size_t)i*CC + c];
      float pv = sF[(size_t)i*CC + c];
      float h = pv*(1.f - uu) + o*uu;
      if(fin){
        dout[(size_t)z*921600 + (size_t)c*3600 + i] = h;
      } else {
        sF[(size_t)i*CC + c] = h;
        unsigned short hh, hl; split_bf(h, hh, hl);
        sTh[(size_t)i*CC + c] = hh; sTl[(size_t)i*CC + c] = hl;
        sCh[(size_t)c*PP + i] = hh; sCl[(size_t)c*PP + i] = hl;
      }
    }
  }
}

extern "C" void kernel_launch(void* const* d_in, const int* in_sizes, int n_in,
                              void* d_out, int out_size, void* d_ws, size_t ws_size,
                              hipStream_t stream){
  char* ws = (char*)d_ws;
  const float* in1   = (const float*)d_in[0];
  const float* in2   = (const float*)d_in[1];
  const float* in3   = (const float*)d_in[2];
  const float* Wlin  = (const float*)d_in[3];
  const float* Wgate = (const float*)d_in[4];
  const float* Wcf   = (const float*)d_in[5];
  const float* bcf   = (const float*)d_in[6];
  const float* Wr    = (const float*)d_in[7];
  const float* br_   = (const float*)d_in[8];
  const float* Wu    = (const float*)d_in[9];
  const float* bu_   = (const float*)d_in[10];
  const float* Wo    = (const float*)d_in[11];
  const float* bo_   = (const float*)d_in[12];

  k_zero<<<dim3(2048), dim3(256), 0, stream>>>(ws);
  k_weights<<<dim3(1024), dim3(256), 0, stream>>>(ws, Wlin, Wu, Wr, Wo, Wcf);
  k_transpose<<<dim3(57, 4, 3), dim3(256), 0, stream>>>(ws, in1, in2, in3);

  for(int rd = 0; rd < 5; rd++){
    k_corr <<<dim3(57, 4, 3), dim3(256), 0, stream>>>(ws);
    k_flash<<<dim3(57, 6),    dim3(256), 0, stream>>>(ws, Wgate);
    k_conv <<<dim3(60, 4, 3), dim3(256), 0, stream>>>(ws, bcf);
    k_gates<<<dim3(57, 8, 3), dim3(256), 0, stream>>>(ws, bu_, br_);
    k_gruo <<<dim3(57, 4, 3), dim3(256), 0, stream>>>(ws, bo_, (float*)d_out, rd == 4 ? 1 : 0);
  }
}